// Round 8
// baseline (79.762 us; speedup 1.0000x reference)
//
#include <hip/hip_runtime.h>

// H[b, i, j], B=64, DIM=500, reference = diag(n^{-s_b}) + corrections of
// magnitude <= ~1.5e-20 (negligible vs 2e-2 absmax threshold) -> zeros + diag.
//
// R7 state: PASSED, dur_us 76.2 = ~45.5us harness 0xAA re-poison (fixed cost,
// 5.9 TB/s) + ~31us fused kernel (~4.3 TB/s). The fused kernel pays div/mod
// per 16B store. This round: split into (1) pure zero-fill at fill-engine
// parity and (2) a 32000-thread diagonal scatter (256 KB), stream-ordered.
//
// Layout (validated R5): out_size/batch == 500000 -> interleaved (re,im)
// pairs; diag complex offset within a batch = n*501. All bounds derived from
// out_size (R4 lesson: never hardcode the allocation size).

#define NK_DIM 500

typedef float nk_f4 __attribute__((ext_vector_type(4)));
typedef float nk_f2 __attribute__((ext_vector_type(2)));

// ---- pass 1: pure zero-fill, no per-iteration math beyond the index bump ----
__global__ void __launch_bounds__(256)
nkat_zero(nk_f4* __restrict__ out4, unsigned total_f4) {
    unsigned stride = gridDim.x * blockDim.x;
    nk_f4 z = (nk_f4){0.f, 0.f, 0.f, 0.f};
    #pragma unroll 4
    for (unsigned t = blockIdx.x * blockDim.x + threadIdx.x; t < total_f4;
         t += stride)
        __builtin_nontemporal_store(z, &out4[t]);   // global_store_dwordx4 nt
}

// ---- pass 2: diagonal scatter, one complex per thread --------------------
template <bool PAIR>
__global__ void __launch_bounds__(256)
nkat_diag(const float* __restrict__ s_real,
          const float* __restrict__ s_imag,
          float* __restrict__ out,
          unsigned total_floats, int total_diag) {
    int t = blockIdx.x * blockDim.x + threadIdx.x;
    if (t >= total_diag) return;
    unsigned b = (unsigned)t / (unsigned)NK_DIM;    // magic-mul
    unsigned n = (unsigned)t - b * (unsigned)NK_DIM;

    float sr = s_real[b];
    float si = s_imag[b];
    float ln = logf((float)(n + 1u));               // ln(1)=0 -> H[b,0,0]=1 exact
    float mag = expf(-sr * ln);
    float ang = si * ln;
    float re = mag * cosf(ang);
    float im = -mag * sinf(ang);

    if (PAIR) {
        // interleaved (re,im): complex idx = b*250000 + n*501, float idx = 2x
        size_t f = 2u * ((size_t)b * (size_t)(NK_DIM * NK_DIM) +
                         (size_t)n * (size_t)(NK_DIM + 1));
        if (f + 1 < (size_t)total_floats)
            *(nk_f2*)(out + f) = (nk_f2){re, im};   // 8B-aligned float2 store
    } else {
        // real-only layout: float idx = b*250000 + n*501
        size_t f = (size_t)b * (size_t)(NK_DIM * NK_DIM) +
                   (size_t)n * (size_t)(NK_DIM + 1);
        if (f < (size_t)total_floats)
            out[f] = re;
    }
}

extern "C" void kernel_launch(void* const* d_in, const int* in_sizes, int n_in,
                              void* d_out, int out_size, void* d_ws, size_t ws_size,
                              hipStream_t stream) {
    const float* s_real = (const float*)d_in[0];
    const float* s_imag = (const float*)d_in[1];
    int batch = in_sizes[0];  // B = 64

    unsigned total_floats = (unsigned)out_size;
    unsigned total_f4 = total_floats / 4u;          // never store past out_size
    unsigned epb = (batch > 0) ? (unsigned)(out_size / batch) : 0u;

    // pass 1: zero everything (134 MB pure-write; target fill-engine ~5.9 TB/s)
    nkat_zero<<<2048, 256, 0, stream>>>((nk_f4*)d_out, total_f4);

    // pass 2: 64*500 diagonal values (stream-ordered after the fill)
    int total_diag = batch * NK_DIM;
    int dgrid = (total_diag + 255) / 256;
    if (epb == (unsigned)(NK_DIM * NK_DIM)) {
        nkat_diag<false><<<dgrid, 256, 0, stream>>>(
            s_real, s_imag, (float*)d_out, total_floats, total_diag);
    } else {
        // validated default: interleaved (re, im) float pairs
        nkat_diag<true><<<dgrid, 256, 0, stream>>>(
            s_real, s_imag, (float*)d_out, total_floats, total_diag);
    }
}

// Round 9
// 77.401 us; speedup vs baseline: 1.0305x; 1.0305x over previous
//
#include <hip/hip_runtime.h>

// H[b, i, j], B=64, DIM=500. Reference output is complex128, but the harness
// casts to float32 => REAL PART ONLY, out_size = 64*500*500 = 16M floats
// (64 MB). Established R8: R4's hardcoded 128 MiB of stores aborted while
// R5's out_size-bounded identical math passed => d_out is 64 MB; the
// epb==250000 real-only branch has been the live path since R5.
//
// Corrections are <= ~1.5e-20 (vs 2e-2 threshold) -> output = zeros + real
// diagonal Re(n^{-s_b}) at float offset b*250000 + n*501.
//
// R8 lesson: our best custom fill = 3.4 TB/s; the ROCm fillBufferAligned
// kernel (used for harness poisoning) = 5.85 TB/s on this exact buffer. So
// zero via hipMemsetAsync (stream-ordered memset node, graph-capturable;
// R1's abort is attributed to its 128MB OOB scatter, not its memset), then
// scatter 32000 real diagonal values.

#define NK_DIM 500

typedef float nk_f2 __attribute__((ext_vector_type(2)));

template <bool PAIR>
__global__ void __launch_bounds__(256)
nkat_diag(const float* __restrict__ s_real,
          const float* __restrict__ s_imag,
          float* __restrict__ out,
          unsigned total_floats, int total_diag) {
    int t = blockIdx.x * blockDim.x + threadIdx.x;
    if (t >= total_diag) return;
    unsigned b = (unsigned)t / (unsigned)NK_DIM;    // magic-mul
    unsigned n = (unsigned)t - b * (unsigned)NK_DIM;

    float sr = s_real[b];
    float si = s_imag[b];
    float ln = logf((float)(n + 1u));               // ln(1)=0 -> H[b,0,0]=1 exact
    float mag = expf(-sr * ln);
    float ang = si * ln;
    float re = mag * cosf(ang);

    if (PAIR) {
        // interleaved (re,im) layout (not the live path; kept memory-safe)
        float im = -mag * sinf(ang);
        size_t f = 2u * ((size_t)b * (size_t)(NK_DIM * NK_DIM) +
                         (size_t)n * (size_t)(NK_DIM + 1));
        if (f + 1 < (size_t)total_floats)
            *(nk_f2*)(out + f) = (nk_f2){re, im};
    } else {
        // real-only layout (live): float idx = b*250000 + n*501
        size_t f = (size_t)b * (size_t)(NK_DIM * NK_DIM) +
                   (size_t)n * (size_t)(NK_DIM + 1);
        if (f < (size_t)total_floats)
            out[f] = re;
    }
}

extern "C" void kernel_launch(void* const* d_in, const int* in_sizes, int n_in,
                              void* d_out, int out_size, void* d_ws, size_t ws_size,
                              hipStream_t stream) {
    const float* s_real = (const float*)d_in[0];
    const float* s_imag = (const float*)d_in[1];
    int batch = in_sizes[0];  // B = 64

    unsigned total_floats = (unsigned)out_size;     // 16M floats = 64 MB
    unsigned epb = (batch > 0) ? (unsigned)(out_size / batch) : 0u;

    // pass 1: zero d_out via the ROCm fill path (5.85 TB/s measured on this
    // buffer; stream-ordered => graph memset node).
    hipMemsetAsync(d_out, 0, (size_t)total_floats * sizeof(float), stream);

    // pass 2: 64*500 diagonal values (stream-ordered after the memset).
    int total_diag = batch * NK_DIM;
    int dgrid = (total_diag + 255) / 256;
    if (epb == 2u * NK_DIM * NK_DIM) {
        nkat_diag<true><<<dgrid, 256, 0, stream>>>(
            s_real, s_imag, (float*)d_out, total_floats, total_diag);
    } else {
        // live path: real-part-only float32 output
        nkat_diag<false><<<dgrid, 256, 0, stream>>>(
            s_real, s_imag, (float*)d_out, total_floats, total_diag);
    }
}